// Round 10
// baseline (183.455 us; speedup 1.0000x reference)
//
#include <hip/hip_runtime.h>
#include <hip/hip_bf16.h>

typedef __attribute__((ext_vector_type(8))) short short8;
typedef __attribute__((ext_vector_type(4))) short short4v;
typedef __attribute__((ext_vector_type(4))) float f32x4;
typedef __attribute__((ext_vector_type(2))) unsigned uint2v;

#define NN 90
#define FD 32
#define LDE 100   // E row stride (cols)
#define LDT 104   // St/Ft row stride (cols)
#define LOG2E 1.4426950408889634f

__device__ inline unsigned short f2bf(float f) {   // RNE via HW cvt (pairs fuse to v_cvt_pk_bf16_f32)
  return __builtin_bit_cast(unsigned short, __float2bfloat16(f));
}
__device__ inline float bf2f(unsigned short h) {
  unsigned u = ((unsigned)h) << 16;
  return __builtin_bit_cast(float, u);
}
// packed pair: low16 = RNE(a), high16 = RNE(b)
__device__ inline unsigned pk2(float a, float b) {
  return (unsigned)f2bf(a) | ((unsigned)f2bf(b) << 16);
}
__device__ inline f32x4 mfma16(short8 a, short8 b, f32x4 c) {
  return __builtin_amdgcn_mfma_f32_16x16x32_bf16(a, b, c, 0, 0, 0);
}
__device__ inline void frag_cvt(f32x4 a, f32x4 b, short8& hi, short8& lo) {
  float v[8] = {a[0], a[1], a[2], a[3], b[0], b[1], b[2], b[3]};
  #pragma unroll
  for (int i = 0; i < 8; ++i) {
    unsigned short h = f2bf(v[i]);
    hi[i] = (short)h;
    lo[i] = (short)f2bf(v[i] - bf2f(h));
  }
}

__global__ __launch_bounds__(256, 5) void CAI_35141422416140_kernel(
    const float* __restrict__ sc, const float* __restrict__ fc,
    const float* __restrict__ we, float* __restrict__ out, int nb)
{
  const int b   = blockIdx.x;
  const int tid = threadIdx.x;
  const int w   = tid >> 6;
  const int l   = tid & 63;
  const int lg  = l >> 4;
  const int lj  = l & 15;

  // LDS 32512 B -> 5 blocks/CU (20 waves/CU)
  __shared__ __align__(16) char lds[32512];
  unsigned short* Ghi = (unsigned short*)(lds + 0);      // [96][40]
  unsigned short* Glo = (unsigned short*)(lds + 7680);   // [96][40]
  unsigned short* E   = (unsigned short*)(lds + 0);      // [96][100] overlays G after bar2
  unsigned short* St  = (unsigned short*)(lds + 19200);  // [32][104]
  unsigned short* Ft  = (unsigned short*)(lds + 25856);  // [32][104]

  const float* Sg = sc + (size_t)b * (NN * FD);
  const float* Fg = fc + (size_t)b * (NN * FD);

  // P1: coalesced scalar loads -> transposed bf16 St/Ft, packed b64 writes
  #pragma unroll
  for (int s = 0; s < 3; ++s) {
    int u  = s * 256 + tid;        // 0..767 = 32 d x 24 n-quads
    int d  = u & 31;
    int n0 = (u >> 5) * 4;         // 0..92
    float sv[4], fv[4];
    #pragma unroll
    for (int r = 0; r < 4; ++r) {
      bool ok = (n0 + r) < NN;
      sv[r] = ok ? Sg[(n0 + r) * FD + d] : 0.f;
      fv[r] = ok ? Fg[(n0 + r) * FD + d] : 0.f;
    }
    uint2v sp = { pk2(sv[0], sv[1]), pk2(sv[2], sv[3]) };
    uint2v fp = { pk2(fv[0], fv[1]), pk2(fv[2], fv[3]) };
    *(uint2v*)&St[d * LDT + n0] = sp;
    *(uint2v*)&Ft[d * LDT + n0] = fp;
  }

  // P0: W B-fragments (hi/lo), pre-scaled by log2e (exp -> exp2)
  short8 Wh[2], Wl[2];
  #pragma unroll
  for (int nt = 0; nt < 2; ++nt) {
    #pragma unroll
    for (int e = 0; e < 8; ++e) {
      float wv = we[(lg * 8 + e) * FD + nt * 16 + lj] * LOG2E;
      unsigned short h = f2bf(wv);
      Wh[nt][e] = (short)h;
      Wl[nt][e] = (short)f2bf(wv - bf2f(h));
    }
  }

  // P2: G = F*W (split precision), 6 row-tiles over 4 waves
  #pragma unroll
  for (int rep = 0; rep < 2; ++rep) {
    int mt = w + rep * 4;
    if (mt <= 5) {
      int row = mt * 16 + lj; if (row > NN - 1) row = NN - 1;
      f32x4 f0 = *(const f32x4*)(Fg + row * FD + lg * 8);
      f32x4 f1 = *(const f32x4*)(Fg + row * FD + lg * 8 + 4);
      short8 fh, fl;
      frag_cvt(f0, f1, fh, fl);
      #pragma unroll
      for (int nt = 0; nt < 2; ++nt) {
        f32x4 g = {0.f, 0.f, 0.f, 0.f};
        g = mfma16(fh, Wh[nt], g);
        g = mfma16(fh, Wl[nt], g);
        g = mfma16(fl, Wh[nt], g);
        #pragma unroll
        for (int q = 0; q < 4; ++q) {
          int grow = mt * 16 + lg * 4 + q;
          unsigned short gh = f2bf(g[q]);
          Ghi[grow * 40 + nt * 16 + lj] = gh;
          Glo[grow * 40 + nt * 16 + lj] = f2bf(g[q] - bf2f(gh));
        }
      }
    }
  }
  __syncthreads();  // bar1: St/Ft + G ready

  // P3: quadrant tiling — wave w: nt in [3*(w>>1),+3), mt in [3*(w&1),+3).
  // Only A tiles (27 MFMA); transpose handled at P5b read time.
  const int ntq = (w >> 1) * 3, mtq = (w & 1) * 3;
  short8 gh8[3], gl8[3];
  #pragma unroll
  for (int im = 0; im < 3; ++im) {
    gh8[im] = *(const short8*)&Ghi[((mtq + im) * 16 + lj) * 40 + lg * 8];
    gl8[im] = *(const short8*)&Glo[((mtq + im) * 16 + lj) * 40 + lg * 8];
  }
  f32x4 a_acc[9];
  #pragma unroll
  for (int in = 0; in < 3; ++in) {
    int row = (ntq + in) * 16 + lj; if (row > NN - 1) row = NN - 1;
    f32x4 s0 = *(const f32x4*)(Sg + row * FD + lg * 8);
    f32x4 s1 = *(const f32x4*)(Sg + row * FD + lg * 8 + 4);
    short8 sh8, sl8;
    frag_cvt(s0, s1, sh8, sl8);
    #pragma unroll
    for (int im = 0; im < 3; ++im) {
      f32x4 a = {0.f, 0.f, 0.f, 0.f};
      a = mfma16(sh8, gh8[im], a);
      a = mfma16(sh8, gl8[im], a);
      a = mfma16(sl8, gh8[im], a);
      a_acc[in * 3 + im] = a;
    }
  }
  __syncthreads();  // bar2: all G reads done; E overlay safe

  // P4: zero pad rows 90..95, then E[m][n] = exp2(a_acc) packed b64 writes
  if (tid < 150) {  // 6 rows x 100 cols x 2B = 1200 B at byte offset 90*200
    uint2v z = {0u, 0u};
    *(uint2v*)(lds + 18000 + tid * 8) = z;
  }
  const unsigned edge_lo = (lg < 3) ? 0xFFFFFFFFu : 0u;  // block-5 cols 4lg+{0,1} < 10
  const unsigned edge_hi = (lg < 2) ? 0xFFFFFFFFu : 0u;  // block-5 cols 4lg+{2,3} < 10
  #pragma unroll
  for (int i = 0; i < 9; ++i) {
    int nt = ntq + i / 3, mt = mtq + i % 3;
    f32x4 a = a_acc[i];
    #pragma unroll
    for (int q = 0; q < 4; ++q) a[q] = __builtin_amdgcn_exp2f(a[q]);
    unsigned a0 = pk2(a[0], a[1]), a1 = pk2(a[2], a[3]);
    if (nt == 5) { a0 &= edge_lo; a1 &= edge_hi; }
    int rowm = mt * 16 + lj;
    if (rowm < NN) {
      uint2v pk = {a0, a1};
      *(uint2v*)&E[rowm * LDE + nt * 16 + lg * 4] = pk;
    }
  }
  __syncthreads();  // bar3: E ready

  const short ONE = (short)0x3F80;  // bf16 1.0
  const short8 ones = {ONE, ONE, ONE, ONE, ONE, ONE, ONE, ONE};
  const size_t ob1 = (size_t)b * (NN * FD);
  const size_t ob2 = (size_t)nb * (NN * FD) + ob1;

  // P5a: cosc[m][d] = sum_n E[m][n]*S[n][d] / colsum[m]
  {
    f32x4 inv; int currb = -1;
    #pragma unroll
    for (int i = 0; i < 3; ++i) {
      int t5 = 3 * w + i;
      int rb = t5 >> 1, dt = t5 & 1;
      bool newrb = (rb != currb);
      int arow = rb * 16 + lj; if (arow > NN - 1) arow = NN - 1;
      f32x4 o  = {0.f, 0.f, 0.f, 0.f};
      f32x4 s4 = {0.f, 0.f, 0.f, 0.f};
      #pragma unroll
      for (int ks = 0; ks < 3; ++ks) {
        short4v a0 = *(const short4v*)&E[arow * LDE + ks * 32 + lg * 8];
        short4v a1 = *(const short4v*)&E[arow * LDE + ks * 32 + lg * 8 + 4];
        short8 af = {a0[0], a0[1], a0[2], a0[3], a1[0], a1[1], a1[2], a1[3]};
        short8 bf = *(const short8*)&St[(dt * 16 + lj) * LDT + ks * 32 + lg * 8];
        o = mfma16(af, bf, o);
        if (newrb) s4 = mfma16(af, ones, s4);
      }
      if (newrb) {
        #pragma unroll
        for (int q = 0; q < 4; ++q) inv[q] = __builtin_amdgcn_rcpf(s4[q]);
        currb = rb;
      }
      #pragma unroll
      for (int q = 0; q < 4; ++q) {
        int m = rb * 16 + lg * 4 + q;
        if (m < NN) out[ob1 + m * FD + dt * 16 + lj] = o[q] * inv[q];
      }
    }
  }

  // P5b: cofc[m][d] = sum_n E[n][m]*F[n][d] / rowsum[m]  (transposed E reads)
  {
    f32x4 inv; int currb = -1;
    #pragma unroll
    for (int i = 0; i < 3; ++i) {
      int t5 = 3 * w + i;
      int rb = t5 >> 1, dt = t5 & 1;
      bool newrb = (rb != currb);
      int acol = rb * 16 + lj;       // output row = E column; rows n are the k axis
      f32x4 o  = {0.f, 0.f, 0.f, 0.f};
      f32x4 s4 = {0.f, 0.f, 0.f, 0.f};
      #pragma unroll
      for (int ks = 0; ks < 3; ++ks) {
        short8 af;
        #pragma unroll
        for (int e = 0; e < 8; ++e) {
          int n = ks * 32 + lg * 8 + e;       // <= 95; rows 90..95 zeroed
          af[e] = (short)E[n * LDE + acol];
        }
        short8 bf = *(const short8*)&Ft[(dt * 16 + lj) * LDT + ks * 32 + lg * 8];
        o = mfma16(af, bf, o);
        if (newrb) s4 = mfma16(af, ones, s4);
      }
      if (newrb) {
        #pragma unroll
        for (int q = 0; q < 4; ++q) inv[q] = __builtin_amdgcn_rcpf(s4[q]);
        currb = rb;
      }
      #pragma unroll
      for (int q = 0; q < 4; ++q) {
        int m = rb * 16 + lg * 4 + q;
        if (m < NN) out[ob2 + m * FD + dt * 16 + lj] = o[q] * inv[q];
      }
    }
  }
}

extern "C" void kernel_launch(void* const* d_in, const int* in_sizes, int n_in,
                              void* d_out, int out_size, void* d_ws, size_t ws_size,
                              hipStream_t stream) {
  const float* sc = (const float*)d_in[0];
  const float* fc = (const float*)d_in[1];
  const float* we = (const float*)d_in[2];
  float* out = (float*)d_out;
  int nb = in_sizes[0] / (NN * FD);  // 8192
  CAI_35141422416140_kernel<<<dim3(nb), dim3(256), 0, stream>>>(sc, fc, we, out, nb);
}

// Round 11
// 106.380 us; speedup vs baseline: 1.7245x; 1.7245x over previous
//
#include <hip/hip_runtime.h>

typedef __attribute__((ext_vector_type(8))) short short8;
typedef __attribute__((ext_vector_type(4))) short short4v;
typedef __attribute__((ext_vector_type(4))) float f32x4;
typedef __attribute__((ext_vector_type(2))) unsigned uint2v;

#define NN 90
#define FD 32
#define LDE 100   // E row stride (cols)
#define LDT 104   // St/Ft row stride (cols)
#define LOG2E 1.4426950408889634f

__device__ inline unsigned short f2bf(float f) {   // branchless RNE (manual — faster than intrinsic, R10 A/B)
  unsigned u = __builtin_bit_cast(unsigned, f);
  return (unsigned short)((u + 0x7fffu + ((u >> 16) & 1u)) >> 16);
}
__device__ inline float bf2f(unsigned short h) {
  unsigned u = ((unsigned)h) << 16;
  return __builtin_bit_cast(float, u);
}
// packed pair: low16 = RNE(a), high16 = RNE(b)
__device__ inline unsigned pk2(float a, float b) {
  unsigned ua = __builtin_bit_cast(unsigned, a);
  unsigned ub = __builtin_bit_cast(unsigned, b);
  return ((ua + 0x7fffu + ((ua >> 16) & 1u)) >> 16) |
         ((ub + 0x7fffu + ((ub >> 16) & 1u)) & 0xFFFF0000u);
}
__device__ inline f32x4 mfma16(short8 a, short8 b, f32x4 c) {
  return __builtin_amdgcn_mfma_f32_16x16x32_bf16(a, b, c, 0, 0, 0);
}
__device__ inline void frag_cvt(f32x4 a, f32x4 b, short8& hi, short8& lo) {
  float v[8] = {a[0], a[1], a[2], a[3], b[0], b[1], b[2], b[3]};
  #pragma unroll
  for (int i = 0; i < 8; ++i) {
    unsigned short h = f2bf(v[i]);
    hi[i] = (short)h;
    lo[i] = (short)(__builtin_bit_cast(unsigned, v[i] - bf2f(h)) >> 16);
  }
}

__global__ __launch_bounds__(256, 5) void CAI_35141422416140_kernel(
    const float* __restrict__ sc, const float* __restrict__ fc,
    const float* __restrict__ we, float* __restrict__ out, int nb)
{
  const int b   = blockIdx.x;
  const int tid = threadIdx.x;
  const int w   = tid >> 6;
  const int l   = tid & 63;
  const int lg  = l >> 4;
  const int lj  = l & 15;

  // LDS 32512 B -> 5 blocks/CU (20 waves/CU)
  __shared__ __align__(16) char lds[32512];
  unsigned short* Ghi = (unsigned short*)(lds + 0);      // [96][40]
  unsigned short* Glo = (unsigned short*)(lds + 7680);   // [96][40]
  unsigned short* E   = (unsigned short*)(lds + 0);      // [96][100] overlays G after bar2
  unsigned short* St  = (unsigned short*)(lds + 19200);  // [32][104]
  unsigned short* Ft  = (unsigned short*)(lds + 25856);  // [32][104]

  const float* Sg = sc + (size_t)b * (NN * FD);
  const float* Fg = fc + (size_t)b * (NN * FD);

  // P-1: prefetch ALL P2/P3 global operands at kernel entry — latency hides
  // under P1 staging + bar1. Indices compile-time after unroll (no scratch).
  const int ntq = (w >> 1) * 3, mtq = (w & 1) * 3;
  int fr0 = w * 16 + lj;                                  // P2 rep0 row (<=63)
  int fr1 = (w + 4) * 16 + lj; if (fr1 > NN - 1) fr1 = NN - 1;  // P2 rep1 row, clamped
  f32x4 pf[2][2];
  pf[0][0] = *(const f32x4*)(Fg + fr0 * FD + lg * 8);
  pf[0][1] = *(const f32x4*)(Fg + fr0 * FD + lg * 8 + 4);
  pf[1][0] = *(const f32x4*)(Fg + fr1 * FD + lg * 8);
  pf[1][1] = *(const f32x4*)(Fg + fr1 * FD + lg * 8 + 4);
  f32x4 ps[3][2];
  #pragma unroll
  for (int in = 0; in < 3; ++in) {
    int row = (ntq + in) * 16 + lj; if (row > NN - 1) row = NN - 1;
    ps[in][0] = *(const f32x4*)(Sg + row * FD + lg * 8);
    ps[in][1] = *(const f32x4*)(Sg + row * FD + lg * 8 + 4);
  }

  // P1: coalesced scalar loads -> transposed bf16 St/Ft, packed b64 writes
  #pragma unroll
  for (int s = 0; s < 3; ++s) {
    int u  = s * 256 + tid;        // 0..767 = 32 d x 24 n-quads
    int d  = u & 31;
    int n0 = (u >> 5) * 4;         // 0..92
    float sv[4], fv[4];
    #pragma unroll
    for (int r = 0; r < 4; ++r) {
      bool ok = (n0 + r) < NN;
      sv[r] = ok ? Sg[(n0 + r) * FD + d] : 0.f;
      fv[r] = ok ? Fg[(n0 + r) * FD + d] : 0.f;
    }
    uint2v sp = { pk2(sv[0], sv[1]), pk2(sv[2], sv[3]) };
    uint2v fp = { pk2(fv[0], fv[1]), pk2(fv[2], fv[3]) };
    *(uint2v*)&St[d * LDT + n0] = sp;
    *(uint2v*)&Ft[d * LDT + n0] = fp;
  }

  // P0: W B-fragments (hi/lo), pre-scaled by log2e (exp -> exp2)
  short8 Wh[2], Wl[2];
  #pragma unroll
  for (int nt = 0; nt < 2; ++nt) {
    #pragma unroll
    for (int e = 0; e < 8; ++e) {
      float wv = we[(lg * 8 + e) * FD + nt * 16 + lj] * LOG2E;
      unsigned short h = f2bf(wv);
      Wh[nt][e] = (short)h;
      Wl[nt][e] = (short)(__builtin_bit_cast(unsigned, wv - bf2f(h)) >> 16);
    }
  }

  // P2: G = F*W (split precision), 6 row-tiles over 4 waves, rows from prefetch
  #pragma unroll
  for (int rep = 0; rep < 2; ++rep) {
    int mt = w + rep * 4;
    if (mt <= 5) {
      short8 fh, fl;
      frag_cvt(pf[rep][0], pf[rep][1], fh, fl);
      #pragma unroll
      for (int nt = 0; nt < 2; ++nt) {
        f32x4 g = {0.f, 0.f, 0.f, 0.f};
        g = mfma16(fh, Wh[nt], g);
        g = mfma16(fh, Wl[nt], g);
        g = mfma16(fl, Wh[nt], g);
        #pragma unroll
        for (int q = 0; q < 4; ++q) {
          int grow = mt * 16 + lg * 4 + q;
          unsigned short gh = f2bf(g[q]);
          Ghi[grow * 40 + nt * 16 + lj] = gh;
          Glo[grow * 40 + nt * 16 + lj] =
              (unsigned short)(__builtin_bit_cast(unsigned, g[q] - bf2f(gh)) >> 16);
        }
      }
    }
  }
  __syncthreads();  // bar1: St/Ft + G ready

  // P3: quadrant tiling — wave w: nt in [3*(w>>1),+3), mt in [3*(w&1),+3).
  // Only A tiles (27 MFMA); transpose handled at P5b read time.
  short8 gh8[3], gl8[3];
  #pragma unroll
  for (int im = 0; im < 3; ++im) {
    gh8[im] = *(const short8*)&Ghi[((mtq + im) * 16 + lj) * 40 + lg * 8];
    gl8[im] = *(const short8*)&Glo[((mtq + im) * 16 + lj) * 40 + lg * 8];
  }
  f32x4 a_acc[9];
  #pragma unroll
  for (int in = 0; in < 3; ++in) {
    short8 sh8, sl8;
    frag_cvt(ps[in][0], ps[in][1], sh8, sl8);
    #pragma unroll
    for (int im = 0; im < 3; ++im) {
      f32x4 a = {0.f, 0.f, 0.f, 0.f};
      a = mfma16(sh8, gh8[im], a);
      a = mfma16(sh8, gl8[im], a);
      a = mfma16(sl8, gh8[im], a);
      a_acc[in * 3 + im] = a;
    }
  }
  __syncthreads();  // bar2: all G reads done; E overlay safe

  // P4: zero pad rows 90..95, then E[m][n] = exp2(a_acc) packed b64 writes
  if (tid < 150) {  // 6 rows x 100 cols x 2B = 1200 B at byte offset 90*200
    uint2v z = {0u, 0u};
    *(uint2v*)(lds + 18000 + tid * 8) = z;
  }
  const unsigned edge_lo = (lg < 3) ? 0xFFFFFFFFu : 0u;  // block-5 cols 4lg+{0,1} < 10
  const unsigned edge_hi = (lg < 2) ? 0xFFFFFFFFu : 0u;  // block-5 cols 4lg+{2,3} < 10
  #pragma unroll
  for (int i = 0; i < 9; ++i) {
    int nt = ntq + i / 3, mt = mtq + i % 3;
    f32x4 a = a_acc[i];
    #pragma unroll
    for (int q = 0; q < 4; ++q) a[q] = __builtin_amdgcn_exp2f(a[q]);
    unsigned a0 = pk2(a[0], a[1]), a1 = pk2(a[2], a[3]);
    if (nt == 5) { a0 &= edge_lo; a1 &= edge_hi; }
    int rowm = mt * 16 + lj;
    if (rowm < NN) {
      uint2v pk = {a0, a1};
      *(uint2v*)&E[rowm * LDE + nt * 16 + lg * 4] = pk;
    }
  }
  __syncthreads();  // bar3: E ready

  const short ONE = (short)0x3F80;  // bf16 1.0
  const short8 ones = {ONE, ONE, ONE, ONE, ONE, ONE, ONE, ONE};
  const size_t ob1 = (size_t)b * (NN * FD);
  const size_t ob2 = (size_t)nb * (NN * FD) + ob1;

  // P5a: cosc[m][d] = sum_n E[m][n]*S[n][d] / colsum[m]
  {
    f32x4 inv; int currb = -1;
    #pragma unroll
    for (int i = 0; i < 3; ++i) {
      int t5 = 3 * w + i;
      int rb = t5 >> 1, dt = t5 & 1;
      bool newrb = (rb != currb);
      int arow = rb * 16 + lj; if (arow > NN - 1) arow = NN - 1;
      f32x4 o  = {0.f, 0.f, 0.f, 0.f};
      f32x4 s4 = {0.f, 0.f, 0.f, 0.f};
      #pragma unroll
      for (int ks = 0; ks < 3; ++ks) {
        short4v a0 = *(const short4v*)&E[arow * LDE + ks * 32 + lg * 8];
        short4v a1 = *(const short4v*)&E[arow * LDE + ks * 32 + lg * 8 + 4];
        short8 af = {a0[0], a0[1], a0[2], a0[3], a1[0], a1[1], a1[2], a1[3]};
        short8 bf = *(const short8*)&St[(dt * 16 + lj) * LDT + ks * 32 + lg * 8];
        o = mfma16(af, bf, o);
        if (newrb) s4 = mfma16(af, ones, s4);
      }
      if (newrb) {
        #pragma unroll
        for (int q = 0; q < 4; ++q) inv[q] = __builtin_amdgcn_rcpf(s4[q]);
        currb = rb;
      }
      #pragma unroll
      for (int q = 0; q < 4; ++q) {
        int m = rb * 16 + lg * 4 + q;
        if (m < NN) out[ob1 + m * FD + dt * 16 + lj] = o[q] * inv[q];
      }
    }
  }

  // P5b: cofc[m][d] = sum_n E[n][m]*F[n][d] / rowsum[m]  (transposed E reads)
  {
    f32x4 inv; int currb = -1;
    #pragma unroll
    for (int i = 0; i < 3; ++i) {
      int t5 = 3 * w + i;
      int rb = t5 >> 1, dt = t5 & 1;
      bool newrb = (rb != currb);
      int acol = rb * 16 + lj;       // output row = E column; rows n are the k axis
      f32x4 o  = {0.f, 0.f, 0.f, 0.f};
      f32x4 s4 = {0.f, 0.f, 0.f, 0.f};
      #pragma unroll
      for (int ks = 0; ks < 3; ++ks) {
        short8 af;
        #pragma unroll
        for (int e = 0; e < 8; ++e) {
          int n = ks * 32 + lg * 8 + e;       // <= 95; rows 90..95 zeroed
          af[e] = (short)E[n * LDE + acol];
        }
        short8 bf = *(const short8*)&Ft[(dt * 16 + lj) * LDT + ks * 32 + lg * 8];
        o = mfma16(af, bf, o);
        if (newrb) s4 = mfma16(af, ones, s4);
      }
      if (newrb) {
        #pragma unroll
        for (int q = 0; q < 4; ++q) inv[q] = __builtin_amdgcn_rcpf(s4[q]);
        currb = rb;
      }
      #pragma unroll
      for (int q = 0; q < 4; ++q) {
        int m = rb * 16 + lg * 4 + q;
        if (m < NN) out[ob2 + m * FD + dt * 16 + lj] = o[q] * inv[q];
      }
    }
  }
}

extern "C" void kernel_launch(void* const* d_in, const int* in_sizes, int n_in,
                              void* d_out, int out_size, void* d_ws, size_t ws_size,
                              hipStream_t stream) {
  const float* sc = (const float*)d_in[0];
  const float* fc = (const float*)d_in[1];
  const float* we = (const float*)d_in[2];
  float* out = (float*)d_out;
  int nb = in_sizes[0] / (NN * FD);  // 8192
  CAI_35141422416140_kernel<<<dim3(nb), dim3(256), 0, stream>>>(sc, fc, we, out, nb);
}